// Round 1
// baseline (1847.587 us; speedup 1.0000x reference)
//
#include <hip/hip_runtime.h>

typedef __bf16 bf16_t;
typedef __bf16 bf16x8 __attribute__((ext_vector_type(8)));
typedef float f32x4 __attribute__((ext_vector_type(4)));

constexpr int NN = 16384;   // nodes
constexpr int F  = 128;     // in/hidden features
constexpr int BM = 64;      // M-tile of big GEMM
constexpr int BK = 64;      // K-tile
constexpr int LDA = 72;     // padded LDS row (bf16 elems): 144 B stride -> 2-way banks (free)
constexpr int LDB = 72;

// ---------------------------------------------------------------------------
// small dense GEMM:  outT[j][i] = sum_k in[i][k] * w[k][j]   (write TRANSPOSED bf16)
// in: fp32 (IN_BF16=false) or bf16 (true); w: fp32 [F][F]
// grid 512 x 256 thr; 32 rows per block
// ---------------------------------------------------------------------------
template<bool IN_BF16>
__global__ __launch_bounds__(256)
void small_gemm_T(const void* __restrict__ inp, const float* __restrict__ w,
                  bf16_t* __restrict__ outT)
{
    __shared__ float xt[32 * 132];           // 32 rows x 128 cols, padded
    const int t  = threadIdx.x;
    const int i0 = blockIdx.x * 32;
    {
        const int r = t >> 3, cc = (t & 7) * 16;
        float* dst = &xt[r * 132 + cc];
        if constexpr (!IN_BF16) {
            const float* src = (const float*)inp + (size_t)(i0 + r) * F + cc;
            float4 v0 = ((const float4*)src)[0];
            float4 v1 = ((const float4*)src)[1];
            float4 v2 = ((const float4*)src)[2];
            float4 v3 = ((const float4*)src)[3];
            ((float4*)dst)[0] = v0; ((float4*)dst)[1] = v1;
            ((float4*)dst)[2] = v2; ((float4*)dst)[3] = v3;
        } else {
            const bf16_t* src = (const bf16_t*)inp + (size_t)(i0 + r) * F + cc;
            bf16x8 v0 = ((const bf16x8*)src)[0];
            bf16x8 v1 = ((const bf16x8*)src)[1];
            #pragma unroll
            for (int q = 0; q < 8; q++) { dst[q] = (float)v0[q]; dst[8 + q] = (float)v1[q]; }
        }
    }
    __syncthreads();
    const int j  = t & 127;
    const int r0 = (t >> 7) * 16;
    float acc[16];
    #pragma unroll
    for (int r = 0; r < 16; r++) acc[r] = 0.f;
    for (int k4 = 0; k4 < F / 4; k4++) {
        const float w0 = w[(k4 * 4 + 0) * F + j];
        const float w1v = w[(k4 * 4 + 1) * F + j];
        const float w2v = w[(k4 * 4 + 2) * F + j];
        const float w3v = w[(k4 * 4 + 3) * F + j];
        #pragma unroll
        for (int r = 0; r < 16; r++) {
            const float4 xv = *(const float4*)&xt[(r0 + r) * 132 + k4 * 4];
            acc[r] += xv.x * w0 + xv.y * w1v + xv.z * w2v + xv.w * w3v;
        }
    }
    bf16_t* dst = outT + (size_t)j * NN + i0 + r0;
    #pragma unroll
    for (int r = 0; r < 16; r++) dst[r] = (bf16_t)acc[r];
}

// ---------------------------------------------------------------------------
// big aggregation GEMM:  H = relu(Aadj @ B + bias)
//   Aadj fp32 [NN][NN] (converted to bf16 during staging)
//   BT   bf16 [F][NN]  (B transposed: BT[n][k])
// FINAL=false: writes Hout bf16 [NN][F]
// FINAL=true : fuses head: out[i][c] = b3[c] + sum_k relu_tile[i][k] * w3[k][c]
// block 256 thr = 4 waves; wave w covers n in [w*32, w*32+32); BM=64 rows/block
// ---------------------------------------------------------------------------
template<bool FINAL>
__global__ __launch_bounds__(256)
void agg_gemm(const float* __restrict__ Aadj, const bf16_t* __restrict__ BT,
              const float* __restrict__ bias, bf16_t* __restrict__ Hout,
              const float* __restrict__ w3, const float* __restrict__ b3,
              float* __restrict__ out)
{
    __shared__ bf16_t sA[BM * LDA];   //  9.2 KB
    __shared__ bf16_t sB[F * LDB];    // 18.4 KB
    const int t = threadIdx.x;
    const int m0 = blockIdx.x * BM;
    const int w = t >> 6, lane = t & 63, quad = lane >> 4, l16 = lane & 15;

    f32x4 acc[4][2];
    #pragma unroll
    for (int mf = 0; mf < 4; mf++)
        #pragma unroll
        for (int nf = 0; nf < 2; nf++) acc[mf][nf] = (f32x4){0.f, 0.f, 0.f, 0.f};

    // staging assignment: A: thread -> row am (0..63), 16 fp32 at col ac
    const int am = t >> 2, ac = (t & 3) * 16;
    const float* aptr = Aadj + (size_t)(m0 + am) * NN + ac;
    bf16_t* sA_dst = &sA[am * LDA + ac];
    // B: thread -> BT row bn (0..127), 32 bf16 at col bc
    const int bn = t >> 1, bc = (t & 1) * 32;
    const bf16_t* bptr = BT + (size_t)bn * NN + bc;
    bf16_t* sB_dst = &sB[bn * LDB + bc];

    float4 av[4];
    bf16x8 bv[4];
    {   // prefetch K-tile 0 into registers
        const float4* ap = (const float4*)aptr;
        av[0] = ap[0]; av[1] = ap[1]; av[2] = ap[2]; av[3] = ap[3];
        const bf16x8* bp = (const bf16x8*)bptr;
        bv[0] = bp[0]; bv[1] = bp[1]; bv[2] = bp[2]; bv[3] = bp[3];
    }

    for (int k0 = 0; k0 < NN; k0 += BK) {
        // registers -> LDS (fp32 -> bf16 convert for A)
        {
            bf16x8 p0, p1;
            const float* fs = (const float*)av;
            #pragma unroll
            for (int q = 0; q < 8; q++) { p0[q] = (bf16_t)fs[q]; p1[q] = (bf16_t)fs[8 + q]; }
            ((bf16x8*)sA_dst)[0] = p0; ((bf16x8*)sA_dst)[1] = p1;
            ((bf16x8*)sB_dst)[0] = bv[0]; ((bf16x8*)sB_dst)[1] = bv[1];
            ((bf16x8*)sB_dst)[2] = bv[2]; ((bf16x8*)sB_dst)[3] = bv[3];
        }
        __syncthreads();
        // prefetch next K-tile (overlaps with MFMA below; wraps harmlessly on last iter)
        {
            const int kn = (k0 + BK < NN) ? (k0 + BK) : 0;
            const float4* ap = (const float4*)(aptr + kn);
            av[0] = ap[0]; av[1] = ap[1]; av[2] = ap[2]; av[3] = ap[3];
            const bf16x8* bp = (const bf16x8*)(bptr + kn);
            bv[0] = bp[0]; bv[1] = bp[1]; bv[2] = bp[2]; bv[3] = bp[3];
        }
        // compute: 2 k-steps of 32, 4 m-frags x 2 n-frags
        #pragma unroll
        for (int ks = 0; ks < 2; ks++) {
            bf16x8 afr[4], bfr[2];
            #pragma unroll
            for (int mf = 0; mf < 4; mf++)
                afr[mf] = *(const bf16x8*)&sA[(mf * 16 + l16) * LDA + ks * 32 + quad * 8];
            #pragma unroll
            for (int nf = 0; nf < 2; nf++)
                bfr[nf] = *(const bf16x8*)&sB[(w * 32 + nf * 16 + l16) * LDB + ks * 32 + quad * 8];
            #pragma unroll
            for (int mf = 0; mf < 4; mf++)
                #pragma unroll
                for (int nf = 0; nf < 2; nf++)
                    acc[mf][nf] = __builtin_amdgcn_mfma_f32_16x16x32_bf16(
                        afr[mf], bfr[nf], acc[mf][nf], 0, 0, 0);
        }
        __syncthreads();
    }

    // epilogue.  C/D layout: row = quad*4 + reg, col = l16 (m89/m91-verified)
    if constexpr (!FINAL) {
        #pragma unroll
        for (int mf = 0; mf < 4; mf++)
            #pragma unroll
            for (int nf = 0; nf < 2; nf++) {
                const int col = w * 32 + nf * 16 + l16;
                const float bvs = bias[col];
                #pragma unroll
                for (int r = 0; r < 4; r++) {
                    const int row = m0 + mf * 16 + quad * 4 + r;
                    float v = acc[mf][nf][r] + bvs;
                    v = v > 0.f ? v : 0.f;
                    Hout[(size_t)row * F + col] = (bf16_t)v;
                }
            }
    } else {
        __shared__ float htile[BM * 132];
        #pragma unroll
        for (int mf = 0; mf < 4; mf++)
            #pragma unroll
            for (int nf = 0; nf < 2; nf++) {
                const int col = w * 32 + nf * 16 + l16;
                const float bvs = bias[col];
                #pragma unroll
                for (int r = 0; r < 4; r++) {
                    const int rl = mf * 16 + quad * 4 + r;
                    float v = acc[mf][nf][r] + bvs;
                    v = v > 0.f ? v : 0.f;
                    htile[rl * 132 + col] = v;
                }
            }
        __syncthreads();
        if (t < 128) {
            const int r = t >> 1, c = t & 1;
            float s = b3[c];
            for (int k = 0; k < F; k++) s += htile[r * 132 + k] * w3[k * 2 + c];
            out[(size_t)(m0 + r) * 2 + c] = s;
        }
    }
}

// ---------------------------------------------------------------------------
extern "C" void kernel_launch(void* const* d_in, const int* in_sizes, int n_in,
                              void* d_out, int out_size, void* d_ws, size_t ws_size,
                              hipStream_t stream)
{
    const float* x   = (const float*)d_in[0];
    const float* adj = (const float*)d_in[1];
    const float* w1  = (const float*)d_in[2];
    const float* b1  = (const float*)d_in[3];
    const float* w2  = (const float*)d_in[4];
    const float* b2  = (const float*)d_in[5];
    const float* w3  = (const float*)d_in[6];
    const float* b3  = (const float*)d_in[7];
    float* out = (float*)d_out;

    // workspace: 3 x 4 MB bf16 buffers
    bf16_t* xw1T = (bf16_t*)d_ws;                 // [F][NN]  (x@w1)^T
    bf16_t* h1   = xw1T + (size_t)F * NN;         // [NN][F]  relu layer-1
    bf16_t* hw2T = h1   + (size_t)NN * F;         // [F][NN]  (h1@w2)^T

    small_gemm_T<false><<<NN / 32, 256, 0, stream>>>((const void*)x, w1, xw1T);
    agg_gemm<false><<<NN / BM, 256, 0, stream>>>(adj, xw1T, b1, h1, nullptr, nullptr, nullptr);
    small_gemm_T<true><<<NN / 32, 256, 0, stream>>>((const void*)h1, w2, hw2T);
    agg_gemm<true><<<NN / BM, 256, 0, stream>>>(adj, hw2T, b2, nullptr, w3, b3, out);
}